// Round 12
// baseline (223.464 us; speedup 1.0000x reference)
//
#include <hip/hip_runtime.h>
#include <hip/hip_bf16.h>
#include <math.h>

#define LHIST 50

typedef __attribute__((ext_vector_type(8))) short bf16x8;
typedef __attribute__((ext_vector_type(8))) unsigned short u16x8;
typedef __attribute__((ext_vector_type(4))) unsigned u32x4;
typedef __attribute__((ext_vector_type(4))) float f32x4;

__device__ __forceinline__ unsigned short f2bf(float f) {
    union { float f; unsigned u; } v; v.f = f;
    unsigned r = v.u + 0x7fff + ((v.u >> 16) & 1);   // RNE
    return (unsigned short)(r >> 16);
}
__device__ __forceinline__ float bf2f(unsigned short h) {
    return __builtin_bit_cast(float, (unsigned)h << 16);
}
__device__ __forceinline__ unsigned pk2(float lo, float hi) {   // v_cvt_pk_bf16_f32
    __hip_bfloat162 h = __float22bfloat162_rn(make_float2(lo, hi));
    unsigned u;
    __builtin_memcpy(&u, &h, 4);
    return u;
}
__device__ __forceinline__ f32x4 mfma16(bf16x8 a, bf16x8 b, f32x4 c) {
    return __builtin_amdgcn_mfma_f32_16x16x32_bf16(a, b, c, 0, 0, 0);
}
// hq = h (bf16) * q (bf16 packed), repacked bf16 — registers only
__device__ __forceinline__ bf16x8 mulqp(u16x8 h, u16x8 qp) {
    u32x4 r;
    r[0] = pk2(bf2f(h[0]) * bf2f(qp[0]), bf2f(h[1]) * bf2f(qp[1]));
    r[1] = pk2(bf2f(h[2]) * bf2f(qp[2]), bf2f(h[3]) * bf2f(qp[3]));
    r[2] = pk2(bf2f(h[4]) * bf2f(qp[4]), bf2f(h[5]) * bf2f(qp[5]));
    r[3] = pk2(bf2f(h[6]) * bf2f(qp[6]), bf2f(h[7]) * bf2f(qp[7]));
    return __builtin_bit_cast(bf16x8, r);
}

// ws float offsets:
//  W13fb  frag bf16 [nt5][ks2][lane][8]   @ 0         (2560 f)   (W1+W3)
//  Bmfb   frag bf16 [nt5][ks2][lane][8]   @ 5120      (2560 f)   (W2-W3)
//  W4fb   frag bf16 [nt5][ks2][lane][8]   @ 7680      (2560 f)   (W4)
//  W1f    frag bf16 [nt16][ks5][lane][8]  @ 10240     (20480 f)
//  W2f    frag bf16 [nt8][ks8][lane][8]   @ 30720     (16384 f)
//  itemb  bf16 [NI*32]                    @ 47104     (NI*16 f)
//  catb   bf16 [NC*32]                    @ 47104+NI*16
//  combined [B][160] fp32                 after catb

__global__ void prep_kernel(const float* __restrict__ aw1,
                            const float* __restrict__ mw1,
                            const float* __restrict__ mw2,
                            const float* __restrict__ item_table,
                            const float* __restrict__ cat_table,
                            int itemN, int catN,
                            unsigned short* __restrict__ W13fb,
                            unsigned short* __restrict__ Bmfb,
                            unsigned short* __restrict__ W4fb,
                            unsigned short* __restrict__ W1f,
                            unsigned short* __restrict__ W2f,
                            unsigned short* __restrict__ itemb,
                            unsigned short* __restrict__ catb) {
    int i = blockIdx.x * 256 + threadIdx.x;
    int i8 = i * 8;
    if (i8 + 7 < itemN) {
        float4 a = *(const float4*)&item_table[i8];
        float4 b = *(const float4*)&item_table[i8 + 4];
        uint4 r;
        r.x = pk2(a.x, a.y); r.y = pk2(a.z, a.w);
        r.z = pk2(b.x, b.y); r.w = pk2(b.z, b.w);
        *(uint4*)&itemb[i8] = r;
    }
    if (i8 + 7 < catN) {
        float4 a = *(const float4*)&cat_table[i8];
        float4 b = *(const float4*)&cat_table[i8 + 4];
        uint4 r;
        r.x = pk2(a.x, a.y); r.y = pk2(a.z, a.w);
        r.z = pk2(b.x, b.y); r.w = pk2(b.z, b.w);
        *(uint4*)&catb[i8] = r;
    }
    if (i < 5120) {
        int kk = i / 80, n = i - kk * 80;
        int nt = n >> 4, colw = n & 15, ks = kk >> 5, r = kk & 31, qd = r >> 3, off = r & 7;
        int d = ((nt * 2 + ks) * 64 + qd * 16 + colw) * 8 + off;
        Bmfb[d]  = f2bf(aw1[(64 + kk) * 80 + n] - aw1[(128 + kk) * 80 + n]);   // W2-W3
        W4fb[d]  = f2bf(aw1[(192 + kk) * 80 + n]);                              // W4
        W13fb[d] = f2bf(aw1[kk * 80 + n] + aw1[(128 + kk) * 80 + n]);           // W1+W3
    }
    if (i < 40960) {
        int kk = i >> 8, n = i & 255;
        int nt = n >> 4, colw = n & 15, ks = kk >> 5, r = kk & 31, qd = r >> 3, off = r & 7;
        W1f[((nt * 5 + ks) * 64 + qd * 16 + colw) * 8 + off] = f2bf(mw1[i]);
    }
    if (i < 32768) {
        int kk = i >> 7, n = i & 127;
        int nt = n >> 4, colw = n & 15, ks = kk >> 5, r = kk & 31, qd = r >> 3, off = r & 7;
        W2f[((nt * 8 + ks) * 64 + qd * 16 + colw) * 8 + off] = f2bf(mw2[i]);
    }
}

// ---------- attention: 2 batches/block, wave = (batch, l-half) — R6 work decomposition ----
// score[l][j] = relu( q.(W1+W3)[j] + h[l].(W2-W3)[:,j] + (h[l]*q).W4[:,j] + ab1[j] ) . aw2
// mi-outer, per-jt fused bias: no persistent accb/hq arrays -> arch VGPRs <= 64 -> 4 waves/SIMD.

#define JT_FUSED(JT) { \
    f32x4 acc = (f32x4){0.f, 0.f, 0.f, 0.f}; \
    acc = mfma16(*(const bf16x8*)&W13fb[((JT * 2 + 0) * 64 + lane) * 8], \
                 __builtin_bit_cast(bf16x8, qbiu), acc); \
    acc = mfma16(*(const bf16x8*)&W13fb[((JT * 2 + 1) * 64 + lane) * 8], \
                 __builtin_bit_cast(bf16x8, qbcu), acc); \
    acc = mfma16(*(const bf16x8*)&Bmfb[((JT * 2 + 0) * 64 + lane) * 8], vib, acc); \
    acc = mfma16(*(const bf16x8*)&Bmfb[((JT * 2 + 1) * 64 + lane) * 8], vcb, acc); \
    acc = mfma16(*(const bf16x8*)&W4fb[((JT * 2 + 0) * 64 + lane) * 8], hqi, acc); \
    acc = mfma16(*(const bf16x8*)&W4fb[((JT * 2 + 1) * 64 + lane) * 8], hqc, acc); \
    float4 b4 = *(const float4*)&ab1[JT * 16 + quad * 4]; \
    float4 a2 = *(const float4*)&aw2[JT * 16 + quad * 4]; \
    p += fmaxf(acc[0] + b4.x, 0.f) * a2.x + fmaxf(acc[1] + b4.y, 0.f) * a2.y \
       + fmaxf(acc[2] + b4.z, 0.f) * a2.z + fmaxf(acc[3] + b4.w, 0.f) * a2.w; }

#define SCORE_MI(VI, VC, PX) { \
    bf16x8 hqi = mulqp(VI, qbiu); \
    bf16x8 hqc = mulqp(VC, qbcu); \
    bf16x8 vib = __builtin_bit_cast(bf16x8, VI); \
    bf16x8 vcb = __builtin_bit_cast(bf16x8, VC); \
    float p = 0.f; \
    JT_FUSED(0) \
    JT_FUSED(1) \
    JT_FUSED(2) \
    JT_FUSED(3) \
    JT_FUSED(4) \
    p += __shfl_xor(p, 16); \
    p += __shfl_xor(p, 32); \
    PX = p; }

#define ATT_ACC(VI, VC, W) { \
    ai0 += (W) * bf2f(VI[0]); ai1 += (W) * bf2f(VI[1]); \
    ai2 += (W) * bf2f(VI[2]); ai3 += (W) * bf2f(VI[3]); \
    ai4 += (W) * bf2f(VI[4]); ai5 += (W) * bf2f(VI[5]); \
    ai6 += (W) * bf2f(VI[6]); ai7 += (W) * bf2f(VI[7]); \
    ac0 += (W) * bf2f(VC[0]); ac1 += (W) * bf2f(VC[1]); \
    ac2 += (W) * bf2f(VC[2]); ac3 += (W) * bf2f(VC[3]); \
    ac4 += (W) * bf2f(VC[4]); ac5 += (W) * bf2f(VC[5]); \
    ac6 += (W) * bf2f(VC[6]); ac7 += (W) * bf2f(VC[7]); }

__global__ void __launch_bounds__(256, 4) attn_kernel(
    const int* __restrict__ cid, const int* __restrict__ cg,
    const int* __restrict__ cc,  const int* __restrict__ hg,
    const int* __restrict__ hc,
    const float* __restrict__ user_table, const float* __restrict__ item_table,
    const float* __restrict__ cat_table,
    const float* __restrict__ ab1, const float* __restrict__ aw2,
    const unsigned short* __restrict__ W13fb, const unsigned short* __restrict__ Bmfb,
    const unsigned short* __restrict__ W4fb,
    const unsigned short* __restrict__ itemb, const unsigned short* __restrict__ catb,
    float* __restrict__ combined)
{
    __shared__ float red[4][1056];     // per-wave private transpose scratch
    __shared__ float sh_sc[2][64];     // scores per batch
    __shared__ float sh_att[4][64];    // per-wave att partial rows

    const int t = threadIdx.x;
    const int wv = t >> 6;
    const int lane = t & 63;
    const int quad = lane >> 4;
    const int col = lane & 15;
    const int bb = wv >> 1;            // batch within block
    const int hwv = wv & 1;            // l-half of this wave
    const int hoff = hwv * 32;
    const int b = blockIdx.x * 2 + bb;

    const int cgb = cg[b], ccb = cc[b];

    // ---- history indices for this wave's 2 l-tiles (l = hoff + mi*16 + col) ----
    const int hb = b * LHIST;
    int l1 = hoff + 16 + col;                    // only tile that can exceed LHIST
    int l1c = (l1 < LHIST) ? l1 : 0;
    int ig0 = hg[hb + hoff + col], ic0 = hc[hb + hoff + col];
    int ig1 = hg[hb + l1c],        ic1 = hc[hb + l1c];
    bool bad0 = (ig0 == 0);
    bool bad1 = (l1 >= LHIST) || (ig1 == 0);

    // ---- h gathers (issue early) ----
    u16x8 vi0 = *(const u16x8*)&itemb[(size_t)ig0 * 32 + quad * 8];
    u16x8 vi1 = *(const u16x8*)&itemb[(size_t)ig1 * 32 + quad * 8];
    u16x8 vc0 = *(const u16x8*)&catb[(size_t)ic0 * 32 + quad * 8];
    u16x8 vc1 = *(const u16x8*)&catb[(size_t)ic1 * 32 + quad * 8];

    // ---- q: load fp32, pack bf16; fp32 dies immediately ----
    u16x8 qbiu, qbcu;
    {
        const float4 qia = *(const float4*)&item_table[(size_t)cgb * 32 + quad * 8];
        const float4 qib = *(const float4*)&item_table[(size_t)cgb * 32 + quad * 8 + 4];
        const float4 qca = *(const float4*)&cat_table[(size_t)ccb * 32 + quad * 8];
        const float4 qcb = *(const float4*)&cat_table[(size_t)ccb * 32 + quad * 8 + 4];
        u32x4 u, v;
        u[0] = pk2(qia.x, qia.y); u[1] = pk2(qia.z, qia.w);
        u[2] = pk2(qib.x, qib.y); u[3] = pk2(qib.z, qib.w);
        v[0] = pk2(qca.x, qca.y); v[1] = pk2(qca.z, qca.w);
        v[2] = pk2(qcb.x, qcb.y); v[3] = pk2(qcb.z, qcb.w);
        qbiu = __builtin_bit_cast(u16x8, u);
        qbcu = __builtin_bit_cast(u16x8, v);
    }

    // ---- score: mi-outer, per-jt fused bias (hq transient, one acc live) ----
    float px0, px1;
    SCORE_MI(vi0, vc0, px0)
    SCORE_MI(vi1, vc1, px1)

    // ---- stage masked scores ----
    if (quad == 0) {
        sh_sc[bb][hoff + col]      = bad0 ? -1e9f : px0;
        sh_sc[bb][hoff + 16 + col] = bad1 ? -1e9f : px1;
    }
    __syncthreads();

    // ---- full softmax over l (both waves of the batch, redundantly) ----
    float sc = (lane < LHIST) ? sh_sc[bb][lane] : -INFINITY;
    float m = sc;
    m = fmaxf(m, __shfl_xor(m, 32));
    m = fmaxf(m, __shfl_xor(m, 16));
    m = fmaxf(m, __shfl_xor(m, 8));
    m = fmaxf(m, __shfl_xor(m, 4));
    m = fmaxf(m, __shfl_xor(m, 2));
    m = fmaxf(m, __shfl_xor(m, 1));
    float e = (lane < LHIST) ? __expf(sc - m) : 0.f;
    float ssum = e;
    ssum += __shfl_xor(ssum, 32);
    ssum += __shfl_xor(ssum, 16);
    ssum += __shfl_xor(ssum, 8);
    ssum += __shfl_xor(ssum, 4);
    ssum += __shfl_xor(ssum, 2);
    ssum += __shfl_xor(ssum, 1);
    float w = e / ssum;

    // ---- weights for this wave's 2 l-tiles ----
    float wl0 = __shfl(w, hoff + col);
    float wl1 = __shfl(w, hoff + 16 + col);

    // ---- att partials (d = quad*8 + j) ----
    float ai0 = 0.f, ai1 = 0.f, ai2 = 0.f, ai3 = 0.f;
    float ai4 = 0.f, ai5 = 0.f, ai6 = 0.f, ai7 = 0.f;
    float ac0 = 0.f, ac1 = 0.f, ac2 = 0.f, ac3 = 0.f;
    float ac4 = 0.f, ac5 = 0.f, ac6 = 0.f, ac7 = 0.f;
    ATT_ACC(vi0, vc0, wl0)
    ATT_ACC(vi1, vc1, wl1)

    // ---- wave-private LDS transpose reduce over the 16 col-lanes ----
    float* myrow = &red[wv][col * 66];
    *(float2*)&myrow[quad * 8 + 0] = make_float2(ai0, ai1);
    *(float2*)&myrow[quad * 8 + 2] = make_float2(ai2, ai3);
    *(float2*)&myrow[quad * 8 + 4] = make_float2(ai4, ai5);
    *(float2*)&myrow[quad * 8 + 6] = make_float2(ai6, ai7);
    *(float2*)&myrow[33 + quad * 8 + 0] = make_float2(ac0, ac1);
    *(float2*)&myrow[33 + quad * 8 + 2] = make_float2(ac2, ac3);
    *(float2*)&myrow[33 + quad * 8 + 4] = make_float2(ac4, ac5);
    *(float2*)&myrow[33 + quad * 8 + 6] = make_float2(ac6, ac7);
    int colIdx = (lane < 32) ? lane : 33 + (lane - 32);
    float s = 0.f;
    #pragma unroll
    for (int c = 0; c < 16; ++c) s += red[wv][c * 66 + colIdx];
    sh_att[wv][lane] = s;
    __syncthreads();

    // ---- write combined [user | cand_item | cand_cat | att] (hwv==0 wave per batch) ----
    if (hwv == 0) {
        float* crow = combined + (size_t)b * 160;
        const int cidb = cid[b];
        crow[lane] = (lane < 32) ? user_table[(size_t)cidb * 32 + lane]
                                 : item_table[(size_t)cgb * 32 + (lane - 32)];
        if (lane < 32) crow[64 + lane] = cat_table[(size_t)ccb * 32 + lane];
        crow[96 + lane] = sh_att[bb * 2][lane] + sh_att[bb * 2 + 1][lane];
    }
}

// ---------- MLP: MFMA, 32 batch rows per 256-thread block (verified R6) ----------
__global__ void __launch_bounds__(256, 4) mlp_kernel(
    const float* __restrict__ combined,
    const unsigned short* __restrict__ W1f, const unsigned short* __restrict__ W2f,
    const float* __restrict__ mb1, const float* __restrict__ mb2,
    const float* __restrict__ mw3, const float* __restrict__ mb3,
    float* __restrict__ out)
{
    __shared__ __align__(16) unsigned short shA1[5120];   // [mt2][ks5][lane][8]
    __shared__ __align__(16) unsigned short shA2[8192];   // [mt2][ks8][lane][8]
    __shared__ float sh_part[4][32];

    const int t = threadIdx.x;
    const int b0 = blockIdx.x * 32;
    const int wv = t >> 6;
    const int lane = t & 63;
    const int quad = lane >> 4;
    const int col = lane & 15;

    for (int i = t; i < 1280; i += 256) {
        int m = i / 40;
        int s = i - m * 40;
        int k0 = s * 4;
        float4 v = *(const float4*)&combined[(size_t)(b0 + m) * 160 + k0];
        int mt = m >> 4, colm = m & 15;
        int ks = k0 >> 5, qd = (k0 >> 3) & 3, off = k0 & 7;
        ushort4 r; r.x = f2bf(v.x); r.y = f2bf(v.y); r.z = f2bf(v.z); r.w = f2bf(v.w);
        *(ushort4*)&shA1[((mt * 5 + ks) * 64 + qd * 16 + colm) * 8 + off] = r;
    }
    __syncthreads();

    f32x4 acc1[2][4];
    #pragma unroll
    for (int mt = 0; mt < 2; ++mt)
        #pragma unroll
        for (int j = 0; j < 4; ++j) acc1[mt][j] = (f32x4){0.f, 0.f, 0.f, 0.f};
    #pragma unroll
    for (int ks = 0; ks < 5; ++ks) {
        bf16x8 a0 = *(const bf16x8*)&shA1[(ks * 64 + lane) * 8];
        bf16x8 a1 = *(const bf16x8*)&shA1[((5 + ks) * 64 + lane) * 8];
        #pragma unroll
        for (int j = 0; j < 4; ++j) {
            int ntg = wv * 4 + j;
            bf16x8 bw = *(const bf16x8*)&W1f[((ntg * 5 + ks) * 64 + lane) * 8];
            acc1[0][j] = __builtin_amdgcn_mfma_f32_16x16x32_bf16(a0, bw, acc1[0][j], 0, 0, 0);
            acc1[1][j] = __builtin_amdgcn_mfma_f32_16x16x32_bf16(a1, bw, acc1[1][j], 0, 0, 0);
        }
    }
    #pragma unroll
    for (int j = 0; j < 4; ++j) {
        int n = (wv * 4 + j) * 16 + col;
        float bj = mb1[n];
        int ks2 = n >> 5, qd2 = (n >> 3) & 3, off2 = n & 7;
        #pragma unroll
        for (int mt = 0; mt < 2; ++mt)
            #pragma unroll
            for (int i = 0; i < 4; ++i) {
                float z = fmaxf(acc1[mt][j][i] + bj, 0.f);
                shA2[((mt * 8 + ks2) * 64 + qd2 * 16 + quad * 4 + i) * 8 + off2] = f2bf(z);
            }
    }
    __syncthreads();

    f32x4 acc2[2][2];
    #pragma unroll
    for (int mt = 0; mt < 2; ++mt)
        #pragma unroll
        for (int jj = 0; jj < 2; ++jj) acc2[mt][jj] = (f32x4){0.f, 0.f, 0.f, 0.f};
    #pragma unroll
    for (int ks = 0; ks < 8; ++ks) {
        bf16x8 a0 = *(const bf16x8*)&shA2[(ks * 64 + lane) * 8];
        bf16x8 a1 = *(const bf16x8*)&shA2[((8 + ks) * 64 + lane) * 8];
        #pragma unroll
        for (int jj = 0; jj < 2; ++jj) {
            int ntg = wv * 2 + jj;
            bf16x8 bw = *(const bf16x8*)&W2f[((ntg * 8 + ks) * 64 + lane) * 8];
            acc2[0][jj] = __builtin_amdgcn_mfma_f32_16x16x32_bf16(a0, bw, acc2[0][jj], 0, 0, 0);
            acc2[1][jj] = __builtin_amdgcn_mfma_f32_16x16x32_bf16(a1, bw, acc2[1][jj], 0, 0, 0);
        }
    }
    #pragma unroll
    for (int mt = 0; mt < 2; ++mt) {
        #pragma unroll
        for (int i = 0; i < 4; ++i) {
            float p = 0.f;
            #pragma unroll
            for (int jj = 0; jj < 2; ++jj) {
                int n = (wv * 2 + jj) * 16 + col;
                float z = fmaxf(acc2[mt][jj][i] + mb2[n], 0.f);
                p += z * mw3[n];
            }
            p += __shfl_xor(p, 1);
            p += __shfl_xor(p, 2);
            p += __shfl_xor(p, 4);
            p += __shfl_xor(p, 8);
            if (col == 0) sh_part[wv][mt * 16 + quad * 4 + i] = p;
        }
    }
    __syncthreads();
    if (t < 32)
        out[b0 + t] = sh_part[0][t] + sh_part[1][t] + sh_part[2][t] + sh_part[3][t] + mb3[0];
}

extern "C" void kernel_launch(void* const* d_in, const int* in_sizes, int n_in,
                              void* d_out, int out_size, void* d_ws, size_t ws_size,
                              hipStream_t stream) {
    const int*   cid = (const int*)d_in[0];
    const int*   cg  = (const int*)d_in[1];
    const int*   cc  = (const int*)d_in[2];
    const int*   hg  = (const int*)d_in[3];
    const int*   hc  = (const int*)d_in[4];
    const float* user_table = (const float*)d_in[5];
    const float* item_table = (const float*)d_in[6];
    const float* cat_table  = (const float*)d_in[7];
    const float* aw1 = (const float*)d_in[8];
    const float* ab1 = (const float*)d_in[9];
    const float* aw2 = (const float*)d_in[10];
    const float* mw1 = (const float*)d_in[12];
    const float* mb1 = (const float*)d_in[13];
    const float* mw2 = (const float*)d_in[14];
    const float* mb2 = (const float*)d_in[15];
    const float* mw3 = (const float*)d_in[16];
    const float* mb3 = (const float*)d_in[17];
    float* out = (float*)d_out;

    const int B = in_sizes[0];                    // 16384
    const int itemN = in_sizes[6];                // NI*32
    const int catN  = in_sizes[7];                // NC*32
    float* ws = (float*)d_ws;
    unsigned short* W13fb = (unsigned short*)ws;
    unsigned short* Bmfb = (unsigned short*)(ws + 5120);
    unsigned short* W4fb = (unsigned short*)(ws + 7680);
    unsigned short* W1f  = (unsigned short*)(ws + 10240);
    unsigned short* W2f  = (unsigned short*)(ws + 30720);
    unsigned short* itemb = (unsigned short*)(ws + 47104);
    unsigned short* catb  = itemb + itemN;
    float* combined = ws + 47104 + (itemN + catN + 1) / 2;

    int n8 = (itemN + 7) / 8;
    int prep_grid = (n8 + 255) / 256;
    if (prep_grid < 160) prep_grid = 160;
    prep_kernel<<<prep_grid, 256, 0, stream>>>(aw1, mw1, mw2, item_table, cat_table,
                                               itemN, catN, W13fb, Bmfb, W4fb, W1f, W2f,
                                               itemb, catb);
    attn_kernel<<<B / 2, 256, 0, stream>>>(cid, cg, cc, hg, hc,
                                           user_table, item_table, cat_table,
                                           ab1, aw2, W13fb, Bmfb, W4fb, itemb, catb, combined);
    mlp_kernel<<<B / 32, 256, 0, stream>>>(combined, W1f, W2f,
                                           mb1, mb2, mw3, mb3, out);
}

// Round 13
// 183.122 us; speedup vs baseline: 1.2203x; 1.2203x over previous
//
#include <hip/hip_runtime.h>
#include <hip/hip_bf16.h>
#include <math.h>

#define LHIST 50

typedef __attribute__((ext_vector_type(8))) short bf16x8;
typedef __attribute__((ext_vector_type(8))) unsigned short u16x8;
typedef __attribute__((ext_vector_type(4))) unsigned u32x4;
typedef __attribute__((ext_vector_type(4))) float f32x4;

__device__ __forceinline__ unsigned short f2bf(float f) {
    union { float f; unsigned u; } v; v.f = f;
    unsigned r = v.u + 0x7fff + ((v.u >> 16) & 1);   // RNE
    return (unsigned short)(r >> 16);
}
__device__ __forceinline__ float bf2f(unsigned short h) {
    return __builtin_bit_cast(float, (unsigned)h << 16);
}
__device__ __forceinline__ unsigned pk2(float lo, float hi) {   // v_cvt_pk_bf16_f32
    __hip_bfloat162 h = __float22bfloat162_rn(make_float2(lo, hi));
    unsigned u;
    __builtin_memcpy(&u, &h, 4);
    return u;
}
__device__ __forceinline__ f32x4 mfma16(bf16x8 a, bf16x8 b, f32x4 c) {
    return __builtin_amdgcn_mfma_f32_16x16x32_bf16(a, b, c, 0, 0, 0);
}
// hq = h (bf16) * q (fp32), repacked bf16 — registers only
__device__ __forceinline__ bf16x8 mulq(u16x8 h, float4 qa, float4 qb) {
    u32x4 r;
    r[0] = pk2(bf2f(h[0]) * qa.x, bf2f(h[1]) * qa.y);
    r[1] = pk2(bf2f(h[2]) * qa.z, bf2f(h[3]) * qa.w);
    r[2] = pk2(bf2f(h[4]) * qb.x, bf2f(h[5]) * qb.y);
    r[3] = pk2(bf2f(h[6]) * qb.z, bf2f(h[7]) * qb.w);
    return __builtin_bit_cast(bf16x8, r);
}

// ws float offsets:
//  W13fb  frag bf16 [nt5][ks2][lane][8]   @ 0         (2560 f)   (W1+W3)
//  Bmfb   frag bf16 [nt5][ks2][lane][8]   @ 5120      (2560 f)   (W2-W3)
//  W4fb   frag bf16 [nt5][ks2][lane][8]   @ 7680      (2560 f)   (W4)
//  W1f    frag bf16 [nt16][ks5][lane][8]  @ 10240     (20480 f)
//  W2f    frag bf16 [nt8][ks8][lane][8]   @ 30720     (16384 f)
//  itemb  bf16 [NI*32]                    @ 47104     (NI*16 f)
//  catb   bf16 [NC*32]                    @ 47104+NI*16
//  combined [B][160] fp32                 after catb

__global__ void prep_kernel(const float* __restrict__ aw1,
                            const float* __restrict__ mw1,
                            const float* __restrict__ mw2,
                            const float* __restrict__ item_table,
                            const float* __restrict__ cat_table,
                            int itemN, int catN,
                            unsigned short* __restrict__ W13fb,
                            unsigned short* __restrict__ Bmfb,
                            unsigned short* __restrict__ W4fb,
                            unsigned short* __restrict__ W1f,
                            unsigned short* __restrict__ W2f,
                            unsigned short* __restrict__ itemb,
                            unsigned short* __restrict__ catb) {
    int i = blockIdx.x * 256 + threadIdx.x;
    int i8 = i * 8;
    if (i8 + 7 < itemN) {
        float4 a = *(const float4*)&item_table[i8];
        float4 b = *(const float4*)&item_table[i8 + 4];
        uint4 r;
        r.x = pk2(a.x, a.y); r.y = pk2(a.z, a.w);
        r.z = pk2(b.x, b.y); r.w = pk2(b.z, b.w);
        *(uint4*)&itemb[i8] = r;
    }
    if (i8 + 7 < catN) {
        float4 a = *(const float4*)&cat_table[i8];
        float4 b = *(const float4*)&cat_table[i8 + 4];
        uint4 r;
        r.x = pk2(a.x, a.y); r.y = pk2(a.z, a.w);
        r.z = pk2(b.x, b.y); r.w = pk2(b.z, b.w);
        *(uint4*)&catb[i8] = r;
    }
    if (i < 5120) {
        int kk = i / 80, n = i - kk * 80;
        int nt = n >> 4, colw = n & 15, ks = kk >> 5, r = kk & 31, qd = r >> 3, off = r & 7;
        int d = ((nt * 2 + ks) * 64 + qd * 16 + colw) * 8 + off;
        Bmfb[d]  = f2bf(aw1[(64 + kk) * 80 + n] - aw1[(128 + kk) * 80 + n]);   // W2-W3
        W4fb[d]  = f2bf(aw1[(192 + kk) * 80 + n]);                              // W4
        W13fb[d] = f2bf(aw1[kk * 80 + n] + aw1[(128 + kk) * 80 + n]);           // W1+W3
    }
    if (i < 40960) {
        int kk = i >> 8, n = i & 255;
        int nt = n >> 4, colw = n & 15, ks = kk >> 5, r = kk & 31, qd = r >> 3, off = r & 7;
        W1f[((nt * 5 + ks) * 64 + qd * 16 + colw) * 8 + off] = f2bf(mw1[i]);
    }
    if (i < 32768) {
        int kk = i >> 7, n = i & 127;
        int nt = n >> 4, colw = n & 15, ks = kk >> 5, r = kk & 31, qd = r >> 3, off = r & 7;
        W2f[((nt * 8 + ks) * 64 + qd * 16 + colw) * 8 + off] = f2bf(mw2[i]);
    }
}

// ---------- attention: 2 batches/block, wave = (batch, l-half) — verified R6 structure ----
// score[l][j] = relu( q.(W1+W3)[j] + h[l].(W2-W3)[:,j] + (h[l]*q).W4[:,j] + ab1[j] ) . aw2
// Weight frags batch-invariant (L1-hot); bias via MFMA; arch-VGPR state fits bound-3 budget.

#define BIAS_JT(JT, OUT) { \
    bf16x8 w0 = *(const bf16x8*)&W13fb[((JT * 2 + 0) * 64 + lane) * 8]; \
    bf16x8 w1 = *(const bf16x8*)&W13fb[((JT * 2 + 1) * 64 + lane) * 8]; \
    f32x4 a = (f32x4){0.f, 0.f, 0.f, 0.f}; \
    a = mfma16(w0, qbi, a); \
    a = mfma16(w1, qbc, a); \
    float4 b4 = *(const float4*)&ab1[JT * 16 + quad * 4]; \
    a[0] += b4.x; a[1] += b4.y; a[2] += b4.z; a[3] += b4.w; \
    OUT = a; }

#define SCORE_JT(JT, ACCB, VIB, VCB, HQI, HQC, P) { \
    bf16x8 a23_0 = *(const bf16x8*)&Bmfb[((JT * 2 + 0) * 64 + lane) * 8]; \
    bf16x8 a23_1 = *(const bf16x8*)&Bmfb[((JT * 2 + 1) * 64 + lane) * 8]; \
    bf16x8 a4_0  = *(const bf16x8*)&W4fb[((JT * 2 + 0) * 64 + lane) * 8]; \
    bf16x8 a4_1  = *(const bf16x8*)&W4fb[((JT * 2 + 1) * 64 + lane) * 8]; \
    f32x4 acc = ACCB; \
    acc = mfma16(a23_0, VIB, acc); \
    acc = mfma16(a23_1, VCB, acc); \
    acc = mfma16(a4_0, HQI, acc); \
    acc = mfma16(a4_1, HQC, acc); \
    float4 a2 = *(const float4*)&aw2[JT * 16 + quad * 4]; \
    P += fmaxf(acc[0], 0.f) * a2.x + fmaxf(acc[1], 0.f) * a2.y \
       + fmaxf(acc[2], 0.f) * a2.z + fmaxf(acc[3], 0.f) * a2.w; }

#define SCORE_MI(VI, VC, HQI, HQC, PX) { \
    bf16x8 vib = __builtin_bit_cast(bf16x8, VI); \
    bf16x8 vcb = __builtin_bit_cast(bf16x8, VC); \
    float p = 0.f; \
    SCORE_JT(0, accb0, vib, vcb, HQI, HQC, p) \
    SCORE_JT(1, accb1, vib, vcb, HQI, HQC, p) \
    SCORE_JT(2, accb2, vib, vcb, HQI, HQC, p) \
    SCORE_JT(3, accb3, vib, vcb, HQI, HQC, p) \
    SCORE_JT(4, accb4, vib, vcb, HQI, HQC, p) \
    p += __shfl_xor(p, 16); \
    p += __shfl_xor(p, 32); \
    PX = p; }

#define ATT_ACC(VI, VC, W) { \
    ai0 += (W) * bf2f(VI[0]); ai1 += (W) * bf2f(VI[1]); \
    ai2 += (W) * bf2f(VI[2]); ai3 += (W) * bf2f(VI[3]); \
    ai4 += (W) * bf2f(VI[4]); ai5 += (W) * bf2f(VI[5]); \
    ai6 += (W) * bf2f(VI[6]); ai7 += (W) * bf2f(VI[7]); \
    ac0 += (W) * bf2f(VC[0]); ac1 += (W) * bf2f(VC[1]); \
    ac2 += (W) * bf2f(VC[2]); ac3 += (W) * bf2f(VC[3]); \
    ac4 += (W) * bf2f(VC[4]); ac5 += (W) * bf2f(VC[5]); \
    ac6 += (W) * bf2f(VC[6]); ac7 += (W) * bf2f(VC[7]); }

__global__ void __launch_bounds__(256, 3) attn_kernel(
    const int* __restrict__ cid, const int* __restrict__ cg,
    const int* __restrict__ cc,  const int* __restrict__ hg,
    const int* __restrict__ hc,
    const float* __restrict__ user_table, const float* __restrict__ item_table,
    const float* __restrict__ cat_table,
    const float* __restrict__ ab1, const float* __restrict__ aw2,
    const unsigned short* __restrict__ W13fb, const unsigned short* __restrict__ Bmfb,
    const unsigned short* __restrict__ W4fb,
    const unsigned short* __restrict__ itemb, const unsigned short* __restrict__ catb,
    float* __restrict__ combined)
{
    __shared__ float red[4][1056];     // per-wave private transpose scratch
    __shared__ float sh_sc[2][64];     // scores per batch
    __shared__ float sh_att[4][64];    // per-wave att partial rows

    const int t = threadIdx.x;
    const int wv = t >> 6;
    const int lane = t & 63;
    const int quad = lane >> 4;
    const int col = lane & 15;
    const int bb = wv >> 1;            // batch within block
    const int hwv = wv & 1;            // l-half of this wave
    const int hoff = hwv * 32;
    const int b = blockIdx.x * 2 + bb;

    const int cgb = cg[b], ccb = cc[b];

    // ---- history indices for this wave's 2 l-tiles (l = hoff + mi*16 + col) ----
    const int hb = b * LHIST;
    int l1 = hoff + 16 + col;                    // only tile that can exceed LHIST
    int l1c = (l1 < LHIST) ? l1 : 0;
    int ig0 = hg[hb + hoff + col], ic0 = hc[hb + hoff + col];
    int ig1 = hg[hb + l1c],        ic1 = hc[hb + l1c];
    bool bad0 = (ig0 == 0);
    bool bad1 = (l1 >= LHIST) || (ig1 == 0);

    // ---- h gathers (issue early; bias MFMAs below overlap the latency) ----
    u16x8 vi0 = *(const u16x8*)&itemb[(size_t)ig0 * 32 + quad * 8];
    u16x8 vi1 = *(const u16x8*)&itemb[(size_t)ig1 * 32 + quad * 8];
    u16x8 vc0 = *(const u16x8*)&catb[(size_t)ic0 * 32 + quad * 8];
    u16x8 vc1 = *(const u16x8*)&catb[(size_t)ic1 * 32 + quad * 8];

    // ---- q fp32 chunks (d = quad*8 .. +7) ----
    const float4 qia = *(const float4*)&item_table[(size_t)cgb * 32 + quad * 8];
    const float4 qib = *(const float4*)&item_table[(size_t)cgb * 32 + quad * 8 + 4];
    const float4 qca = *(const float4*)&cat_table[(size_t)ccb * 32 + quad * 8];
    const float4 qcb = *(const float4*)&cat_table[(size_t)ccb * 32 + quad * 8 + 4];

    // ---- bias accumulators via MFMA (independent of gathers) ----
    f32x4 accb0, accb1, accb2, accb3, accb4;
    {
        u32x4 u, v;
        u[0] = pk2(qia.x, qia.y); u[1] = pk2(qia.z, qia.w);
        u[2] = pk2(qib.x, qib.y); u[3] = pk2(qib.z, qib.w);
        v[0] = pk2(qca.x, qca.y); v[1] = pk2(qca.z, qca.w);
        v[2] = pk2(qcb.x, qcb.y); v[3] = pk2(qcb.z, qcb.w);
        bf16x8 qbi = __builtin_bit_cast(bf16x8, u);
        bf16x8 qbc = __builtin_bit_cast(bf16x8, v);
        BIAS_JT(0, accb0)
        BIAS_JT(1, accb1)
        BIAS_JT(2, accb2)
        BIAS_JT(3, accb3)
        BIAS_JT(4, accb4)
    }

    // ---- hq frags (q fp32 dies here) ----
    bf16x8 hqi0 = mulq(vi0, qia, qib);
    bf16x8 hqc0 = mulq(vc0, qca, qcb);
    bf16x8 hqi1 = mulq(vi1, qia, qib);
    bf16x8 hqc1 = mulq(vc1, qca, qcb);

    // ---- score MFMAs ----
    float px0, px1;
    SCORE_MI(vi0, vc0, hqi0, hqc0, px0)
    SCORE_MI(vi1, vc1, hqi1, hqc1, px1)

    // ---- stage masked scores ----
    if (quad == 0) {
        sh_sc[bb][hoff + col]      = bad0 ? -1e9f : px0;
        sh_sc[bb][hoff + 16 + col] = bad1 ? -1e9f : px1;
    }
    __syncthreads();

    // ---- full softmax over l (both waves of the batch, redundantly) ----
    float sc = (lane < LHIST) ? sh_sc[bb][lane] : -INFINITY;
    float m = sc;
    m = fmaxf(m, __shfl_xor(m, 32));
    m = fmaxf(m, __shfl_xor(m, 16));
    m = fmaxf(m, __shfl_xor(m, 8));
    m = fmaxf(m, __shfl_xor(m, 4));
    m = fmaxf(m, __shfl_xor(m, 2));
    m = fmaxf(m, __shfl_xor(m, 1));
    float e = (lane < LHIST) ? __expf(sc - m) : 0.f;
    float ssum = e;
    ssum += __shfl_xor(ssum, 32);
    ssum += __shfl_xor(ssum, 16);
    ssum += __shfl_xor(ssum, 8);
    ssum += __shfl_xor(ssum, 4);
    ssum += __shfl_xor(ssum, 2);
    ssum += __shfl_xor(ssum, 1);
    float w = e / ssum;

    // ---- weights for this wave's 2 l-tiles ----
    float wl0 = __shfl(w, hoff + col);
    float wl1 = __shfl(w, hoff + 16 + col);

    // ---- att partials (d = quad*8 + j) ----
    float ai0 = 0.f, ai1 = 0.f, ai2 = 0.f, ai3 = 0.f;
    float ai4 = 0.f, ai5 = 0.f, ai6 = 0.f, ai7 = 0.f;
    float ac0 = 0.f, ac1 = 0.f, ac2 = 0.f, ac3 = 0.f;
    float ac4 = 0.f, ac5 = 0.f, ac6 = 0.f, ac7 = 0.f;
    ATT_ACC(vi0, vc0, wl0)
    ATT_ACC(vi1, vc1, wl1)

    // ---- wave-private LDS transpose reduce over the 16 col-lanes ----
    float* myrow = &red[wv][col * 66];
    *(float2*)&myrow[quad * 8 + 0] = make_float2(ai0, ai1);
    *(float2*)&myrow[quad * 8 + 2] = make_float2(ai2, ai3);
    *(float2*)&myrow[quad * 8 + 4] = make_float2(ai4, ai5);
    *(float2*)&myrow[quad * 8 + 6] = make_float2(ai6, ai7);
    *(float2*)&myrow[33 + quad * 8 + 0] = make_float2(ac0, ac1);
    *(float2*)&myrow[33 + quad * 8 + 2] = make_float2(ac2, ac3);
    *(float2*)&myrow[33 + quad * 8 + 4] = make_float2(ac4, ac5);
    *(float2*)&myrow[33 + quad * 8 + 6] = make_float2(ac6, ac7);
    int colIdx = (lane < 32) ? lane : 33 + (lane - 32);
    float s = 0.f;
    #pragma unroll
    for (int c = 0; c < 16; ++c) s += red[wv][c * 66 + colIdx];
    sh_att[wv][lane] = s;
    __syncthreads();

    // ---- write combined [user | cand_item | cand_cat | att] (hwv==0 wave per batch) ----
    if (hwv == 0) {
        float* crow = combined + (size_t)b * 160;
        const int cidb = cid[b];
        crow[lane] = (lane < 32) ? user_table[(size_t)cidb * 32 + lane]
                                 : item_table[(size_t)cgb * 32 + (lane - 32)];
        if (lane < 32) crow[64 + lane] = cat_table[(size_t)ccb * 32 + lane];
        crow[96 + lane] = sh_att[bb * 2][lane] + sh_att[bb * 2 + 1][lane];
    }
}

// ---------- MLP: MFMA, 32 batch rows per 256-thread block (verified R6) ----------
__global__ void __launch_bounds__(256, 4) mlp_kernel(
    const float* __restrict__ combined,
    const unsigned short* __restrict__ W1f, const unsigned short* __restrict__ W2f,
    const float* __restrict__ mb1, const float* __restrict__ mb2,
    const float* __restrict__ mw3, const float* __restrict__ mb3,
    float* __restrict__ out)
{
    __shared__ __align__(16) unsigned short shA1[5120];   // [mt2][ks5][lane][8]
    __shared__ __align__(16) unsigned short shA2[8192];   // [mt2][ks8][lane][8]
    __shared__ float sh_part[4][32];

    const int t = threadIdx.x;
    const int b0 = blockIdx.x * 32;
    const int wv = t >> 6;
    const int lane = t & 63;
    const int quad = lane >> 4;
    const int col = lane & 15;

    for (int i = t; i < 1280; i += 256) {
        int m = i / 40;
        int s = i - m * 40;
        int k0 = s * 4;
        float4 v = *(const float4*)&combined[(size_t)(b0 + m) * 160 + k0];
        int mt = m >> 4, colm = m & 15;
        int ks = k0 >> 5, qd = (k0 >> 3) & 3, off = k0 & 7;
        ushort4 r; r.x = f2bf(v.x); r.y = f2bf(v.y); r.z = f2bf(v.z); r.w = f2bf(v.w);
        *(ushort4*)&shA1[((mt * 5 + ks) * 64 + qd * 16 + colm) * 8 + off] = r;
    }
    __syncthreads();

    f32x4 acc1[2][4];
    #pragma unroll
    for (int mt = 0; mt < 2; ++mt)
        #pragma unroll
        for (int j = 0; j < 4; ++j) acc1[mt][j] = (f32x4){0.f, 0.f, 0.f, 0.f};
    #pragma unroll
    for (int ks = 0; ks < 5; ++ks) {
        bf16x8 a0 = *(const bf16x8*)&shA1[(ks * 64 + lane) * 8];
        bf16x8 a1 = *(const bf16x8*)&shA1[((5 + ks) * 64 + lane) * 8];
        #pragma unroll
        for (int j = 0; j < 4; ++j) {
            int ntg = wv * 4 + j;
            bf16x8 bw = *(const bf16x8*)&W1f[((ntg * 5 + ks) * 64 + lane) * 8];
            acc1[0][j] = __builtin_amdgcn_mfma_f32_16x16x32_bf16(a0, bw, acc1[0][j], 0, 0, 0);
            acc1[1][j] = __builtin_amdgcn_mfma_f32_16x16x32_bf16(a1, bw, acc1[1][j], 0, 0, 0);
        }
    }
    #pragma unroll
    for (int j = 0; j < 4; ++j) {
        int n = (wv * 4 + j) * 16 + col;
        float bj = mb1[n];
        int ks2 = n >> 5, qd2 = (n >> 3) & 3, off2 = n & 7;
        #pragma unroll
        for (int mt = 0; mt < 2; ++mt)
            #pragma unroll
            for (int i = 0; i < 4; ++i) {
                float z = fmaxf(acc1[mt][j][i] + bj, 0.f);
                shA2[((mt * 8 + ks2) * 64 + qd2 * 16 + quad * 4 + i) * 8 + off2] = f2bf(z);
            }
    }
    __syncthreads();

    f32x4 acc2[2][2];
    #pragma unroll
    for (int mt = 0; mt < 2; ++mt)
        #pragma unroll
        for (int jj = 0; jj < 2; ++jj) acc2[mt][jj] = (f32x4){0.f, 0.f, 0.f, 0.f};
    #pragma unroll
    for (int ks = 0; ks < 8; ++ks) {
        bf16x8 a0 = *(const bf16x8*)&shA2[(ks * 64 + lane) * 8];
        bf16x8 a1 = *(const bf16x8*)&shA2[((8 + ks) * 64 + lane) * 8];
        #pragma unroll
        for (int jj = 0; jj < 2; ++jj) {
            int ntg = wv * 2 + jj;
            bf16x8 bw = *(const bf16x8*)&W2f[((ntg * 8 + ks) * 64 + lane) * 8];
            acc2[0][jj] = __builtin_amdgcn_mfma_f32_16x16x32_bf16(a0, bw, acc2[0][jj], 0, 0, 0);
            acc2[1][jj] = __builtin_amdgcn_mfma_f32_16x16x32_bf16(a1, bw, acc2[1][jj], 0, 0, 0);
        }
    }
    #pragma unroll
    for (int mt = 0; mt < 2; ++mt) {
        #pragma unroll
        for (int i = 0; i < 4; ++i) {
            float p = 0.f;
            #pragma unroll
            for (int jj = 0; jj < 2; ++jj) {
                int n = (wv * 2 + jj) * 16 + col;
                float z = fmaxf(acc2[mt][jj][i] + mb2[n], 0.f);
                p += z * mw3[n];
            }
            p += __shfl_xor(p, 1);
            p += __shfl_xor(p, 2);
            p += __shfl_xor(p, 4);
            p += __shfl_xor(p, 8);
            if (col == 0) sh_part[wv][mt * 16 + quad * 4 + i] = p;
        }
    }
    __syncthreads();
    if (t < 32)
        out[b0 + t] = sh_part[0][t] + sh_part[1][t] + sh_part[2][t] + sh_part[3][t] + mb3[0];
}

extern "C" void kernel_launch(void* const* d_in, const int* in_sizes, int n_in,
                              void* d_out, int out_size, void* d_ws, size_t ws_size,
                              hipStream_t stream) {
    const int*   cid = (const int*)d_in[0];
    const int*   cg  = (const int*)d_in[1];
    const int*   cc  = (const int*)d_in[2];
    const int*   hg  = (const int*)d_in[3];
    const int*   hc  = (const int*)d_in[4];
    const float* user_table = (const float*)d_in[5];
    const float* item_table = (const float*)d_in[6];
    const float* cat_table  = (const float*)d_in[7];
    const float* aw1 = (const float*)d_in[8];
    const float* ab1 = (const float*)d_in[9];
    const float* aw2 = (const float*)d_in[10];
    const float* mw1 = (const float*)d_in[12];
    const float* mb1 = (const float*)d_in[13];
    const float* mw2 = (const float*)d_in[14];
    const float* mb2 = (const float*)d_in[15];
    const float* mw3 = (const float*)d_in[16];
    const float* mb3 = (const float*)d_in[17];
    float* out = (float*)d_out;

    const int B = in_sizes[0];                    // 16384
    const int itemN = in_sizes[6];                // NI*32
    const int catN  = in_sizes[7];                // NC*32
    float* ws = (float*)d_ws;
    unsigned short* W13fb = (unsigned short*)ws;
    unsigned short* Bmfb = (unsigned short*)(ws + 5120);
    unsigned short* W4fb = (unsigned short*)(ws + 7680);
    unsigned short* W1f  = (unsigned short*)(ws + 10240);
    unsigned short* W2f  = (unsigned short*)(ws + 30720);
    unsigned short* itemb = (unsigned short*)(ws + 47104);
    unsigned short* catb  = itemb + itemN;
    float* combined = ws + 47104 + (itemN + catN + 1) / 2;

    int n8 = (itemN + 7) / 8;
    int prep_grid = (n8 + 255) / 256;
    if (prep_grid < 160) prep_grid = 160;
    prep_kernel<<<prep_grid, 256, 0, stream>>>(aw1, mw1, mw2, item_table, cat_table,
                                               itemN, catN, W13fb, Bmfb, W4fb, W1f, W2f,
                                               itemb, catb);
    attn_kernel<<<B / 2, 256, 0, stream>>>(cid, cg, cc, hg, hc,
                                           user_table, item_table, cat_table,
                                           ab1, aw2, W13fb, Bmfb, W4fb, itemb, catb, combined);
    mlp_kernel<<<B / 32, 256, 0, stream>>>(combined, W1f, W2f,
                                           mb1, mb2, mw3, mb3, out);
}